// Round 6
// baseline (41.068 us; speedup 1.0000x reference)
//
#include <hip/hip_runtime.h>
#include <math.h>

// Health_State_Analysis: B=16384 rows, S=2560 fp32 -> 15 stats/row.
// Single kernel, ONE wave per row (40 elems/lane, coalesced interleave),
// no LDS / no barriers. DPP wave reductions; packed f32 pass-1; lag-correlation
// algebra for Hjorth; exact-f32-boundary outlier count; inline f64 finalize on
// lane 63. d_ws unused.

typedef float f32x2 __attribute__((ext_vector_type(2)));
typedef float f32x4 __attribute__((ext_vector_type(4)));

constexpr int S_LEN = 2560;

#define DPP_ADD_F32(x, ctrl) do { \
    int t_ = __builtin_amdgcn_update_dpp(0, __float_as_int(x), ctrl, 0xf, 0xf, false); \
    x += __int_as_float(t_); } while (0)
#define DPP_MAX_F32(x, ctrl) do { \
    int t_ = __builtin_amdgcn_update_dpp(__float_as_int(x), __float_as_int(x), ctrl, 0xf, 0xf, false); \
    x = fmaxf(x, __int_as_float(t_)); } while (0)
#define DPP_MIN_F32(x, ctrl) do { \
    int t_ = __builtin_amdgcn_update_dpp(__float_as_int(x), __float_as_int(x), ctrl, 0xf, 0xf, false); \
    x = fminf(x, __int_as_float(t_)); } while (0)

__device__ __forceinline__ float wave_sum_f32(float x) {
    DPP_ADD_F32(x, 0x111); DPP_ADD_F32(x, 0x112); DPP_ADD_F32(x, 0x114);
    DPP_ADD_F32(x, 0x118); DPP_ADD_F32(x, 0x142); DPP_ADD_F32(x, 0x143);
    return x;  // total in lane 63
}
__device__ __forceinline__ float wave_max_f32(float x) {
    DPP_MAX_F32(x, 0x111); DPP_MAX_F32(x, 0x112); DPP_MAX_F32(x, 0x114);
    DPP_MAX_F32(x, 0x118); DPP_MAX_F32(x, 0x142); DPP_MAX_F32(x, 0x143);
    return x;
}
__device__ __forceinline__ float wave_min_f32(float x) {
    DPP_MIN_F32(x, 0x111); DPP_MIN_F32(x, 0x112); DPP_MIN_F32(x, 0x114);
    DPP_MIN_F32(x, 0x118); DPP_MIN_F32(x, 0x142); DPP_MIN_F32(x, 0x143);
    return x;
}
__device__ __forceinline__ double wave_sum_f64(double x) {
#define DPP_ADD_F64(ctrl) do { \
    long long b_ = __double_as_longlong(x); \
    int lo_ = __builtin_amdgcn_update_dpp(0, (int)(b_ & 0xffffffffLL), ctrl, 0xf, 0xf, false); \
    int hi_ = __builtin_amdgcn_update_dpp(0, (int)(b_ >> 32), ctrl, 0xf, 0xf, false); \
    x += __longlong_as_double(((long long)hi_ << 32) | (unsigned int)lo_); } while (0)
    DPP_ADD_F64(0x111); DPP_ADD_F64(0x112); DPP_ADD_F64(0x114);
    DPP_ADD_F64(0x118); DPP_ADD_F64(0x142); DPP_ADD_F64(0x143);
#undef DPP_ADD_F64
    return x;  // total in lane 63
}
__device__ __forceinline__ double readlane_f64(double x, int l) {
    long long b = __double_as_longlong(x);
    int lo = __builtin_amdgcn_readlane((int)(b & 0xffffffffLL), l);
    int hi = __builtin_amdgcn_readlane((int)(b >> 32), l);
    return __longlong_as_double(((long long)hi << 32) | (unsigned int)lo);
}

__global__ __launch_bounds__(256, 6)
void health_stats(const float* __restrict__ in, float* __restrict__ out) {
    const int lane = threadIdx.x & 63;
    const int wid  = threadIdx.x >> 6;       // 0..3
    const int row  = blockIdx.x * 4 + wid;   // one wave per row

    const f32x4* rp = reinterpret_cast<const f32x4*>(in)
                    + (size_t)row * (S_LEN / 4) + lane;

    // ---- load whole row into wave registers (10 coalesced 1KB wave-loads) ----
    f32x4 X[10];
#pragma unroll
    for (int k = 0; k < 10; ++k) X[k] = rp[k * 64];

    // row endpoints x[0], x[1] as wave-uniform SGPRs (lane 0's first chunk)
    const float ep0 = __int_as_float(__builtin_amdgcn_readlane(__float_as_int(X[0][0]), 0));
    const float ep1 = __int_as_float(__builtin_amdgcn_readlane(__float_as_int(X[0][1]), 0));

    // ---- pass 1: fully packed raw sums / abs / max / min ----
    f32x2 sp = {0.f, 0.f}, qp = {0.f, 0.f}, sabsp = {0.f, 0.f};
    f32x2 vmaxp = {-INFINITY, -INFINITY}, vminp = {INFINITY, INFINITY};
#pragma unroll
    for (int k = 0; k < 10; ++k) {
        f32x2 lo = __builtin_shufflevector(X[k], X[k], 0, 1);
        f32x2 hi = __builtin_shufflevector(X[k], X[k], 2, 3);
        sp += lo + hi;
        qp = __builtin_elementwise_fma(lo, lo, qp);
        qp = __builtin_elementwise_fma(hi, hi, qp);
        sabsp += __builtin_elementwise_max(lo, -lo);   // v_pk_max with neg mod
        sabsp += __builtin_elementwise_max(hi, -hi);
        vmaxp = __builtin_elementwise_max(vmaxp, __builtin_elementwise_max(lo, hi));
        vminp = __builtin_elementwise_min(vminp, __builtin_elementwise_min(lo, hi));
    }

    const double sum_l = (double)sp.x + (double)sp.y;
    const double sq_l  = (double)qp.x + (double)qp.y;
    const double tsum = readlane_f64(wave_sum_f64(sum_l), 63);  // uniform SGPR f64
    const double tsq  = readlane_f64(wave_sum_f64(sq_l), 63);

    // reduce pass-1 f32 stats now (frees the packed pairs before pass 2)
    float sabs_t = wave_sum_f32(sabsp.x + sabsp.y);
    float vmax_t = wave_max_f32(fmaxf(vmaxp.x, vmaxp.y));
    float vmin_t = wave_min_f32(fminf(vminp.x, vminp.y));

    const double mean = tsum * (1.0 / S_LEN);
    const double var  = (tsq - tsum * mean) * (1.0 / (S_LEN - 1));  // n*mean^2 ~1 << tsq: no cancellation
    const double stdv = sqrt(var);
    const double thr  = 3.0 * stdv;

    // exact f32 decision boundaries: (x > bhi_f64) <=> (x > RD_f32(bhi)), bhi>0;
    // (x < blo_f64) <=> (x < RU_f32(blo)), blo<0. One bits-step toward 0 each.
    const double bhi = mean + thr, blo = mean - thr;
    float bhi_f = (float)bhi;
    if ((double)bhi_f > bhi) bhi_f = __int_as_float(__float_as_int(bhi_f) - 1);
    float blo_f = (float)blo;
    if ((double)blo_f < blo) blo_f = __int_as_float(__float_as_int(blo_f) - 1);

    const float mf = (float)mean;
    const f32x2 nmf2 = {-mf, -mf};
    const int nli = (lane + 1) & 63;

    // ---- pass 2: packed moments, outliers, zcr, lag correlations ----
    f32x2 c3p = {0.f, 0.f}, c4p = {0.f, 0.f};
    float r1 = 0.f, r2 = 0.f;
    int outc = 0, zcc = 0;

#pragma unroll
    for (int k = 0; k < 10; ++k) {
        const float x0 = X[k][0], x1 = X[k][1], x2v = X[k][2], x3 = X[k][3];
        // next-two-elements: lane<63 <- lane+1's chunk k; lane63 <- lane0's
        // chunk k+1 (push-value trick). For k==9 lane0 pushes 0.0 -> lane63's
        // nonexistent neighbor becomes 0, which zeroes the invalid lag products.
        float v0, v1;
        if (k < 9) {
            v0 = (lane == 0) ? X[k + 1][0] : x0;
            v1 = (lane == 0) ? X[k + 1][1] : x1;
        } else {
            v0 = (lane == 0) ? 0.f : x0;
            v1 = (lane == 0) ? 0.f : x1;
        }
        const float n0 = __shfl(v0, nli);
        const float n1 = __shfl(v1, nli);

        f32x2 lo = __builtin_shufflevector(X[k], X[k], 0, 1);
        f32x2 hi = __builtin_shufflevector(X[k], X[k], 2, 3);
        f32x2 cl = lo + nmf2, ch = hi + nmf2;
        f32x2 ql = cl * cl,  qh = ch * ch;
        c3p = __builtin_elementwise_fma(ql, cl, c3p);
        c3p = __builtin_elementwise_fma(qh, ch, c3p);
        c4p = __builtin_elementwise_fma(ql, ql, c4p);
        c4p = __builtin_elementwise_fma(qh, qh, c4p);

        outc += __popcll(__ballot(x0  > bhi_f || x0  < blo_f));
        outc += __popcll(__ballot(x1  > bhi_f || x1  < blo_f));
        outc += __popcll(__ballot(x2v > bhi_f || x2v < blo_f));
        outc += __popcll(__ballot(x3  > bhi_f || x3  < blo_f));

        const unsigned long long m0 = __ballot(x0  < 0.f);
        const unsigned long long m1 = __ballot(x1  < 0.f);
        const unsigned long long m2 = __ballot(x2v < 0.f);
        const unsigned long long m3 = __ballot(x3  < 0.f);
        const unsigned long long mn = __ballot(n0  < 0.f);
        zcc += __popcll(m0 ^ m1) + __popcll(m1 ^ m2) + __popcll(m2 ^ m3);
        // k==9: bit 63 compares x[2559] vs injected 0 -> mask it off
        zcc += __popcll((m3 ^ mn) & ((k == 9) ? 0x7FFFFFFFFFFFFFFFULL : ~0ULL));

        // lag-1 / lag-2 correlation partials (tail products vanish via n=0)
        r1 = fmaf(x0, x1, fmaf(x1, x2v, fmaf(x2v, x3, fmaf(x3, n0, r1))));
        r2 = fmaf(x0, x2v, fmaf(x1, x3, fmaf(x2v, n0, fmaf(x3, n1, r2))));
    }

    const float c3_t = wave_sum_f32(c3p.x + c3p.y);
    const float c4_t = wave_sum_f32(c4p.x + c4p.y);
    const float r1_t = wave_sum_f32(r1);
    const float r2_t = wave_sum_f32(r2);

    // ---- inline finalize: lane 63 holds all reduction totals ----
    if (lane == 63) {
        const double rms  = sqrt(tsq * (1.0 / S_LEN));
        const double m3d  = (double)c3_t * (1.0 / S_LEN);
        const double m4d  = (double)c4_t * (1.0 / S_LEN);
        const double skew = m3d / (var * stdv);
        const double kurt = m4d / (var * var);
        const float  amax = fmaxf(fabsf(vmax_t), fabsf(vmin_t));
        const double shape   = rms * (double)S_LEN / (double)sabs_t;
        const double impulse = (double)amax * (double)S_LEN / (double)sabs_t;

        // Hjorth via lag-correlation identities (x[2558], x[2559] live here):
        const double e0 = (double)ep0, e1 = (double)ep1;
        const double e2 = (double)X[9][2], e3 = (double)X[9][3];
        const double Q = tsq, r1d = (double)r1_t, r2d = (double)r2_t;
        const double s1q = 2.0 * Q - 2.0 * r1d - e0 * e0 - e3 * e3;
        const double s2q = 6.0 * Q - 8.0 * r1d + 2.0 * r2d
                         + 4.0 * (e0 * e1 + e2 * e3)
                         - 5.0 * e0 * e0 - e1 * e1 - e2 * e2 - 5.0 * e3 * e3;
        const double sd1 = e3 - e0;
        const double sd2 = (e3 - e2) - (e1 - e0);
        const double var1 = (s1q - sd1 * sd1 * (1.0 / (S_LEN - 1))) * (1.0 / (S_LEN - 2));
        const double var2 = (s2q - sd2 * sd2 * (1.0 / (S_LEN - 2))) * (1.0 / (S_LEN - 3));

        float* o = out + (size_t)row * 15;
        o[0]  = (float)mean;
        o[1]  = vmax_t;
        o[2]  = vmin_t;
        o[3]  = vmax_t - vmin_t;
        o[4]  = (float)var;
        o[5]  = (float)rms;
        o[6]  = (float)skew;
        o[7]  = (float)kurt;
        o[8]  = (float)shape;
        o[9]  = (float)impulse;
        o[10] = (float)outc;
        o[11] = (float)zcc * (1.0f / (2.0f * S_LEN));
        o[12] = (float)var;
        o[13] = (float)sqrt(var1 / var);
        o[14] = (float)sqrt(var2 / var1);
    }
}

extern "C" void kernel_launch(void* const* d_in, const int* in_sizes, int n_in,
                              void* d_out, int out_size, void* d_ws, size_t ws_size,
                              hipStream_t stream) {
    (void)in_sizes; (void)n_in; (void)d_ws; (void)ws_size; (void)out_size;
    const float* in = (const float*)d_in[0];
    float* out = (float*)d_out;
    // 16384 rows, 4 rows per 256-thread block (1 wave per row), single kernel
    health_stats<<<4096, 256, 0, stream>>>(in, out);
}